// Round 14
// baseline (415.826 us; speedup 1.0000x reference)
//
#include <hip/hip_runtime.h>
#include <hip/hip_bf16.h>

#define BB 2
#define SS 2048
#define INC 64
#define HIDN 512
#define NHH 8
#define HDD 64

typedef __attribute__((ext_vector_type(8))) short bf16x8;
typedef __attribute__((ext_vector_type(4))) float f32x4;

__device__ __forceinline__ short f2bf(float f) {
  union { __hip_bfloat16 h; short s; } u;
  u.h = __float2bfloat16(f);
  return u.s;
}
__device__ __forceinline__ float bf2f(short s) {
  return __uint_as_float(((unsigned)(unsigned short)s) << 16);
}

// ---------------------------------------------------------------------------
// prep: bf16 weights. Wallbf = concat(Wq,Wk,Wv) rows (n,k) = 1536x512;
// Wobf = Wo (n,k); Wkpbf/Wvpbf = 64x64; ball = concat qkv biases.
// ---------------------------------------------------------------------------
__global__ __launch_bounds__(256) void prep_kernel(
    const float* __restrict__ Wq, const float* __restrict__ Wk_,
    const float* __restrict__ Wv_, const float* __restrict__ bq,
    const float* __restrict__ bk_, const float* __restrict__ bv_,
    const float* __restrict__ Wo, const float* __restrict__ Wkp,
    const float* __restrict__ Wvp, short* __restrict__ Wallbf,
    float* __restrict__ ball, short* __restrict__ Wobf,
    short* __restrict__ Wkpbf, short* __restrict__ Wvpbf) {
  int i0 = blockIdx.x * 256 + threadIdx.x;
  int stride = gridDim.x * 256;
  for (int idx = i0; idx < 786432; idx += stride) {
    float v;
    if (idx < 262144)      v = Wq[idx];
    else if (idx < 524288) v = Wk_[idx - 262144];
    else                   v = Wv_[idx - 524288];
    Wallbf[idx] = f2bf(v);
  }
  for (int idx = i0; idx < 262144; idx += stride) Wobf[idx] = f2bf(Wo[idx]);
  for (int idx = i0; idx < 4096; idx += stride) {
    Wkpbf[idx] = f2bf(Wkp[idx]);
    Wvpbf[idx] = f2bf(Wvp[idx]);
  }
  if (i0 < 1536) {
    float v;
    if (i0 < 512)       v = bq[i0];
    else if (i0 < 1024) v = bk_[i0 - 512];
    else                v = bv_[i0 - 1024];
    ball[i0] = v;
  }
}

// ---------------------------------------------------------------------------
// conv: TS=4 rows/block (1024 blocks, 4 waves/SIMD) for occupancy.
// ---------------------------------------------------------------------------
#define CTS 4
template <int KW, int OFF>
__device__ __forceinline__ void conv_channel(const float* __restrict__ w,
                                             const float* xs, float bias,
                                             float acc[CTS]) {
#pragma unroll
  for (int i = 0; i < CTS; i++) acc[i] = bias;
#pragma unroll 4
  for (int ci = 0; ci < 64; ci++) {
    float xv[CTS + KW - 1];
#pragma unroll
    for (int r = 0; r < CTS + KW - 1; r++) xv[r] = xs[(r + OFF) * 64 + ci];
#pragma unroll
    for (int k = 0; k < KW; k++) {
      float wv = w[ci * KW + k];
#pragma unroll
      for (int i = 0; i < CTS; i++) acc[i] += xv[i + k] * wv;
    }
  }
}

__global__ __launch_bounds__(256) void conv_kernel(
    const float* __restrict__ x, const float* __restrict__ w1,
    const float* __restrict__ b1, const float* __restrict__ w2,
    const float* __restrict__ b2, const float* __restrict__ w3,
    const float* __restrict__ b3, float* __restrict__ h,
    short* __restrict__ hbf) {
  int blk = blockIdx.x;                 // 1024 blocks
  int b = blk / (SS / CTS);
  int s0 = (blk % (SS / CTS)) * CTS;
  __shared__ float xs[(CTS + 6) * 64];
  int tid = threadIdx.x;
  for (int i = tid; i < (CTS + 6) * 64; i += 256) {
    int row = i >> 6, ci = i & 63;
    int sgl = s0 + row - 3;
    xs[i] = (sgl >= 0 && sgl < SS) ? x[(b * SS + sgl) * 64 + ci] : 0.f;
  }
  __syncthreads();
  for (int c = tid; c < 512; c += 256) {
    float acc[CTS];
    if (c < 171) {
      conv_channel<3, 2>(w1 + c * (64 * 3), xs, b1[c], acc);
    } else if (c < 342) {
      conv_channel<5, 1>(w2 + (c - 171) * (64 * 5), xs, b2[c - 171], acc);
    } else {
      conv_channel<7, 0>(w3 + (c - 342) * (64 * 7), xs, b3[c - 342], acc);
    }
#pragma unroll
    for (int i = 0; i < CTS; i++) {
      float v = fmaxf(acc[i], 0.f);
      int idx = (b * SS + s0 + i) * 512 + c;
      h[idx] = v;
      hbf[idx] = f2bf(v);
    }
  }
}

// ---------------------------------------------------------------------------
// MFMA QKV gemm: 64-row blocks (grid 64x24 = 1536, 6 blocks/CU).
// Wave = one 16-row m-tile x 64 cols. Double-buffered register prefetch.
// ---------------------------------------------------------------------------
__global__ __launch_bounds__(256, 4) void gemm_qkv(
    const short* __restrict__ Abf, const short* __restrict__ Wbf,
    const float* __restrict__ bias, short* __restrict__ Qh,
    short* __restrict__ Kh, short* __restrict__ Vh) {
  int m0 = blockIdx.x * 64;
  int n0 = blockIdx.y * 64;
  int tid = threadIdx.x;
  int wvv = tid >> 6, lane = tid & 63;
  int quad = lane >> 4, l16 = lane & 15;
  int mw = m0 + wvv * 16;
  const short* ap = Abf + (size_t)(mw + l16) * 512 + quad * 8;
  const short* bp = Wbf + (size_t)(n0 + l16) * 512 + quad * 8;
  f32x4 acc[4] = {};
  bf16x8 cA = *(const bf16x8*)ap;
  bf16x8 cB0 = *(const bf16x8*)(bp + 0 * 16 * 512);
  bf16x8 cB1 = *(const bf16x8*)(bp + 1 * 16 * 512);
  bf16x8 cB2 = *(const bf16x8*)(bp + 2 * 16 * 512);
  bf16x8 cB3 = *(const bf16x8*)(bp + 3 * 16 * 512);
#pragma unroll 1
  for (int ks = 0; ks < 16; ks++) {
    int offn = (ks + 1 < 16 ? ks + 1 : 15) * 32;
    bf16x8 nA = *(const bf16x8*)(ap + offn);
    bf16x8 nB0 = *(const bf16x8*)(bp + 0 * 16 * 512 + offn);
    bf16x8 nB1 = *(const bf16x8*)(bp + 1 * 16 * 512 + offn);
    bf16x8 nB2 = *(const bf16x8*)(bp + 2 * 16 * 512 + offn);
    bf16x8 nB3 = *(const bf16x8*)(bp + 3 * 16 * 512 + offn);
    acc[0] = __builtin_amdgcn_mfma_f32_16x16x32_bf16(cA, cB0, acc[0], 0, 0, 0);
    acc[1] = __builtin_amdgcn_mfma_f32_16x16x32_bf16(cA, cB1, acc[1], 0, 0, 0);
    acc[2] = __builtin_amdgcn_mfma_f32_16x16x32_bf16(cA, cB2, acc[2], 0, 0, 0);
    acc[3] = __builtin_amdgcn_mfma_f32_16x16x32_bf16(cA, cB3, acc[3], 0, 0, 0);
    cA = nA;
    cB0 = nB0; cB1 = nB1; cB2 = nB2; cB3 = nB3;
  }
  int which = n0 >> 9;
  int head = (n0 >> 6) & 7;
  short* dst = which == 0 ? Qh : (which == 1 ? Kh : Vh);
  float scale = which == 0 ? 0.125f : 1.0f;
#pragma unroll
  for (int r = 0; r < 4; r++) {
    int m = mw + quad * 4 + r;
    int bb = m >> 11, s = m & 2047;
    size_t rowoff = ((size_t)(bb * 8 + head) * 2048 + s) * 64;
#pragma unroll
    for (int t = 0; t < 4; t++) {
      int hd = t * 16 + l16;
      float v = acc[t][r] + bias[n0 + hd];
      dst[rowoff + hd] = f2bf(v * scale);
    }
  }
}

// ---------------------------------------------------------------------------
// kpvp via MFMA: 64-row blocks (512 blocks, 2/CU). Wave = 16 rows.
// ---------------------------------------------------------------------------
__global__ __launch_bounds__(256, 4) void kpvp_kernel(
    const short* __restrict__ Kh, const short* __restrict__ Vh,
    const short* __restrict__ Wkpbf, const float* __restrict__ bkp,
    const short* __restrict__ Wvpbf, const float* __restrict__ bvp,
    short* __restrict__ Kph, float* __restrict__ Vp) {
  int m0 = blockIdx.x * 64;             // 512 blocks over 32768 rows
  int tid = threadIdx.x;
  int wvv = tid >> 6, lane = tid & 63;
  int quad = lane >> 4, l16 = lane & 15;
  int mw = m0 + wvv * 16;
  {
    const short* ap = Kh + (size_t)(mw + l16) * 64 + quad * 8;
    const short* bp = Wkpbf + l16 * 64 + quad * 8;
    bf16x8 A0 = *(const bf16x8*)ap, A1 = *(const bf16x8*)(ap + 32);
    f32x4 acc[4] = {};
#pragma unroll
    for (int t = 0; t < 4; t++) {
      bf16x8 B0 = *(const bf16x8*)(bp + t * 16 * 64);
      bf16x8 B1 = *(const bf16x8*)(bp + t * 16 * 64 + 32);
      acc[t] = __builtin_amdgcn_mfma_f32_16x16x32_bf16(A0, B0, acc[t], 0, 0, 0);
      acc[t] = __builtin_amdgcn_mfma_f32_16x16x32_bf16(A1, B1, acc[t], 0, 0, 0);
    }
#pragma unroll
    for (int r = 0; r < 4; r++) {
      int m = mw + quad * 4 + r;
#pragma unroll
      for (int t = 0; t < 4; t++) {
        int n = t * 16 + l16;
        Kph[(size_t)m * 64 + n] = f2bf(acc[t][r] + bkp[n]);
      }
    }
  }
  {
    const short* ap = Vh + (size_t)(mw + l16) * 64 + quad * 8;
    const short* bp = Wvpbf + l16 * 64 + quad * 8;
    bf16x8 A0 = *(const bf16x8*)ap, A1 = *(const bf16x8*)(ap + 32);
    f32x4 acc[4] = {};
#pragma unroll
    for (int t = 0; t < 4; t++) {
      bf16x8 B0 = *(const bf16x8*)(bp + t * 16 * 64);
      bf16x8 B1 = *(const bf16x8*)(bp + t * 16 * 64 + 32);
      acc[t] = __builtin_amdgcn_mfma_f32_16x16x32_bf16(A0, B0, acc[t], 0, 0, 0);
      acc[t] = __builtin_amdgcn_mfma_f32_16x16x32_bf16(A1, B1, acc[t], 0, 0, 0);
    }
#pragma unroll
    for (int r = 0; r < 4; r++) {
      int m = mw + quad * 4 + r;
#pragma unroll
      for (int t = 0; t < 4; t++) {
        int n = t * 16 + l16;
        Vp[(size_t)m * 64 + n] = acc[t][r] + bvp[n];
      }
    }
  }
}

// ---------------------------------------------------------------------------
// local windowed attention, MFMA on bf16: one wave per 16-query tile.
// ---------------------------------------------------------------------------
__global__ __launch_bounds__(256) void local_attn(
    const short* __restrict__ Qh, const short* __restrict__ Kh,
    const short* __restrict__ Vh, float* __restrict__ ctxl) {
  int wv = threadIdx.x >> 6;
  int tile = blockIdx.x * 4 + wv;       // 0..2047
  int bh = tile >> 7;
  int q0 = (tile & 127) * 16;
  int lane = threadIdx.x & 63;
  int quad = lane >> 4, l16 = lane & 15;

  __shared__ float Sloc[4][2][16][17];
  __shared__ float wloc[4][16][8];

  const short* qbase = Qh + (size_t)(bh * 2048 + q0 + l16) * 64 + quad * 8;
  bf16x8 a0 = *(const bf16x8*)qbase;
  bf16x8 a1 = *(const bf16x8*)(qbase + 32);

  int k0a = min(max(q0 - 2 + l16, 0), 2047);
  int k1a = min(q0 + 6 + l16, 2047);
  const short* kb0 = Kh + (size_t)(bh * 2048 + k0a) * 64 + quad * 8;
  const short* kb1 = Kh + (size_t)(bh * 2048 + k1a) * 64 + quad * 8;
  bf16x8 B00 = *(const bf16x8*)kb0;
  bf16x8 B01 = *(const bf16x8*)(kb0 + 32);
  bf16x8 B10 = *(const bf16x8*)kb1;
  bf16x8 B11 = *(const bf16x8*)(kb1 + 32);
  f32x4 C0 = {0.f, 0.f, 0.f, 0.f};
  f32x4 C1 = {0.f, 0.f, 0.f, 0.f};
  C0 = __builtin_amdgcn_mfma_f32_16x16x32_bf16(a0, B00, C0, 0, 0, 0);
  C0 = __builtin_amdgcn_mfma_f32_16x16x32_bf16(a1, B01, C0, 0, 0, 0);
  C1 = __builtin_amdgcn_mfma_f32_16x16x32_bf16(a0, B10, C1, 0, 0, 0);
  C1 = __builtin_amdgcn_mfma_f32_16x16x32_bf16(a1, B11, C1, 0, 0, 0);
#pragma unroll
  for (int r = 0; r < 4; r++) {
    Sloc[wv][0][quad * 4 + r][l16] = C0[r];
    Sloc[wv][1][quad * 4 + r][l16] = C1[r];
  }
  __builtin_amdgcn_wave_barrier();
  if (lane < 16) {
    int q = lane;
    float sc[5];
    bool ok[5];
#pragma unroll
    for (int j = 0; j < 5; j++) {
      int offq = q + j - 2;
      int sg = q0 + offq;
      ok[j] = (sg >= 0 && sg < SS);
      int t = offq <= 13 ? 0 : 1;
      int col = t ? offq - 6 : offq + 2;
      sc[j] = ok[j] ? Sloc[wv][t][q][col] : -3.0e38f;
    }
    float m = -3.0e38f;
#pragma unroll
    for (int j = 0; j < 5; j++) m = fmaxf(m, sc[j]);
    float e[5], l = 0.f;
#pragma unroll
    for (int j = 0; j < 5; j++) {
      e[j] = ok[j] ? __expf(sc[j] - m) : 0.f;
      l += e[j];
    }
    float inv = 1.f / l;
#pragma unroll
    for (int j = 0; j < 5; j++) wloc[wv][q][j] = e[j] * inv;
  }
  __builtin_amdgcn_wave_barrier();
  {
    int q = lane >> 2, jb = (lane & 3) * 16;
    int s = q0 + q;
    float acc[16] = {};
#pragma unroll
    for (int j = 0; j < 5; j++) {
      int sg = s + j - 2;
      if (sg >= 0 && sg < SS) {
        float w = wloc[wv][q][j];
        const short* vr = Vh + (size_t)(bh * 2048 + sg) * 64 + jb;
#pragma unroll
        for (int u = 0; u < 16; u += 4) {
          short4 v4 = *(const short4*)(vr + u);
          acc[u + 0] += w * bf2f(v4.x);
          acc[u + 1] += w * bf2f(v4.y);
          acc[u + 2] += w * bf2f(v4.z);
          acc[u + 3] += w * bf2f(v4.w);
        }
      }
    }
    float* orow = ctxl + (size_t)(bh * 2048 + s) * 64 + jb;
#pragma unroll
    for (int u = 0; u < 16; u += 4)
      *(float4*)(orow + u) =
          make_float4(acc[u], acc[u + 1], acc[u + 2], acc[u + 3]);
  }
}

// ---------------------------------------------------------------------------
// global sparse attention — R8 single-pass depth-8 insert, 2-wide ILP,
// launch_bounds(256,4).
// ---------------------------------------------------------------------------
__global__ __launch_bounds__(256, 4) void global_attn(
    const short* __restrict__ Qh, const short* __restrict__ Kph,
    const float* __restrict__ Vp, const float* __restrict__ Wvp,
    const float* __restrict__ bvp, const float* __restrict__ ctxl,
    short* __restrict__ ctxcb) {
  int wid = blockIdx.x;                // 2048
  int bh = wid >> 7;
  int q0 = (wid & 127) * 16;
  int b = bh >> 3, hh = bh & 7;
  int tid = threadIdx.x;
  int wv = tid >> 6;
  int lane = tid & 63;
  int quad = lane >> 4, l16 = lane & 15;

  __shared__ unsigned mer[4][16][17];
  __shared__ float tw[16][17];
  __shared__ int   tix[16][17];
  __shared__ float spr[16][68];

  const short* qbase = Qh + (size_t)(bh * 2048 + q0 + l16) * 64 + quad * 8;
  bf16x8 a0 = *(const bf16x8*)qbase;
  bf16x8 a1 = *(const bf16x8*)(qbase + 32);

  const short* kbase =
      Kph + (size_t)(bh * 2048 + wv * 512 + l16) * 64 + quad * 8;

  unsigned e0[8], e1[8], e2[8], e3[8];
#pragma unroll
  for (int j = 0; j < 8; j++) { e0[j] = 0; e1[j] = 0; e2[j] = 0; e3[j] = 0; }

  auto insert8 = [&](unsigned (&er)[8], unsigned cand) {
    unsigned p = cand;
#pragma unroll
    for (int j = 0; j < 8; j++) {
      unsigned cur = er[j];
      unsigned hi = cur > p ? cur : p;   // v_max_u32
      p = cur > p ? p : cur;             // v_min_u32
      er[j] = hi;
    }
  };
  auto mkcand = [&](float s, int idxr) -> unsigned {
    unsigned u = __float_as_uint(s);
    u ^= ((unsigned)((int)u >> 31)) | 0x80000000u;
    return (u & 0xFFFFF800u) | (unsigned)idxr;
  };

  int idxbase = 2047 - (wv * 512 + l16);
  {
    bf16x8 B00 = *(const bf16x8*)kbase;
    bf16x8 B01 = *(const bf16x8*)(kbase + 32);
    bf16x8 B10 = *(const bf16x8*)(kbase + 1024);
    bf16x8 B11 = *(const bf16x8*)(kbase + 1024 + 32);
#pragma unroll 1
    for (int g = 0; g < 32; g += 2) {
      int g2 = (g + 2 < 32) ? g + 2 : 30;
      int g3 = (g + 3 < 32) ? g + 3 : 31;
      bf16x8 P00 = *(const bf16x8*)(kbase + g2 * 1024);
      bf16x8 P01 = *(const bf16x8*)(kbase + g2 * 1024 + 32);
      bf16x8 P10 = *(const bf16x8*)(kbase + g3 * 1024);
      bf16x8 P11 = *(const bf16x8*)(kbase + g3 * 1024 + 32);
      f32x4 C0 = {0.f, 0.f, 0.f, 0.f};
      f32x4 C1 = {0.f, 0.f, 0.f, 0.f};
      C0 = __builtin_amdgcn_mfma_f32_16x16x32_bf16(a0, B00, C0, 0, 0, 0);
      C0 = __builtin_amdgcn_mfma_f32_16x16x32_bf16(a1, B01, C0, 0, 0, 0);
      C1 = __builtin_amdgcn_mfma_f32_16x16x32_bf16(a0, B10, C1, 0, 0, 0);
      C1 = __builtin_amdgcn_mfma_f32_16x16x32_bf16(a1, B11, C1, 0, 0, 0);
      int idxr0 = idxbase - (g << 4);
      int idxr1 = idxbase - ((g + 1) << 4);
      insert8(e0, mkcand(C0[0], idxr0));
      insert8(e1, mkcand(C0[1], idxr0));
      insert8(e2, mkcand(C0[2], idxr0));
      insert8(e3, mkcand(C0[3], idxr0));
      insert8(e0, mkcand(C1[0], idxr1));
      insert8(e1, mkcand(C1[1], idxr1));
      insert8(e2, mkcand(C1[2], idxr1));
      insert8(e3, mkcand(C1[3], idxr1));
      B00 = P00; B01 = P01; B10 = P10; B11 = P11;
    }
  }

  auto wmerge = [&](unsigned (&er)[8], int r) {
#pragma unroll
    for (int t = 0; t < 16; t++) {
      unsigned w = er[0];
#pragma unroll
      for (int mm = 1; mm <= 8; mm <<= 1) {
        unsigned o = (unsigned)__shfl_xor((int)w, mm);
        w = w > o ? w : o;
      }
      if (er[0] == w) {
#pragma unroll
        for (int j = 0; j < 7; j++) er[j] = er[j + 1];
        er[7] = 0;
      }
      if (l16 == r) mer[wv][quad * 4 + r][t] = w;
    }
  };
  wmerge(e0, 0);
  wmerge(e1, 1);
  wmerge(e2, 2);
  wmerge(e3, 3);
  __syncthreads();

  if (tid < 16) {
    int q = tid;
    unsigned h0 = mer[0][q][0], h1 = mer[1][q][0];
    unsigned h2 = mer[2][q][0], h3 = mer[3][q][0];
    int p0 = 1, p1 = 1, p2 = 1, p3 = 1;
    float mval = 0.f, lsum = 0.f;
    float ev[16];
    int kit[16];
#pragma unroll
    for (int t = 0; t < 16; t++) {
      unsigned w01 = h0 > h1 ? h0 : h1;
      unsigned w23 = h2 > h3 ? h2 : h3;
      unsigned w = w01 > w23 ? w01 : w23;
      if (w == h0)      { h0 = p0 < 16 ? mer[0][q][p0] : 0u; p0++; }
      else if (w == h1) { h1 = p1 < 16 ? mer[1][q][p1] : 0u; p1++; }
      else if (w == h2) { h2 = p2 < 16 ? mer[2][q][p2] : 0u; p2++; }
      else              { h3 = p3 < 16 ? mer[3][q][p3] : 0u; p3++; }
      unsigned wvv = w & 0xFFFFF800u;
      unsigned uu = (w & 0x80000000u) ? (wvv ^ 0x80000000u) : ~wvv;
      float sv = (w == 0u) ? -1.0e30f : __uint_as_float(uu);
      int ki = 2047 - (int)(w & 0x7FFu);
      if (t == 0) mval = sv;
      float ex = __expf(sv - mval);
      lsum += ex;
      ev[t] = ex;
      kit[t] = ki;
    }
    float inv = 1.f / lsum;
#pragma unroll
    for (int j = 0; j < 16; j++) {
      tw[q][j] = ev[j] * inv;
      tix[q][j] = kit[j];
    }
  }
  __syncthreads();

  {
    int q = tid >> 4, rl = (tid & 15) * 4;
    float ax = 0.f, ay = 0.f, az = 0.f, aw = 0.f;
#pragma unroll 4
    for (int j = 0; j < 16; j++) {
      float w = tw[q][j];
      const float* vrow = Vp + (size_t)(bh * 2048 + tix[q][j]) * 64 + rl;
      float4 v = *(const float4*)vrow;
      ax += w * v.x; ay += w * v.y; az += w * v.z; aw += w * v.w;
    }
    *(float4*)&spr[q][rl] = make_float4(ax, ay, az, aw);
  }
  __syncthreads();

  {
    int q = tid >> 4, jb = (tid & 15) * 4;
    float c0 = bvp[jb], c1 = bvp[jb + 1], c2 = bvp[jb + 2], c3 = bvp[jb + 3];
    for (int r = 0; r < 64; r += 4) {
      float4 sp4 = *(const float4*)&spr[q][r];
      float4 w0 = *(const float4*)(Wvp + (jb + 0) * 64 + r);
      float4 w1 = *(const float4*)(Wvp + (jb + 1) * 64 + r);
      float4 w2 = *(const float4*)(Wvp + (jb + 2) * 64 + r);
      float4 w3 = *(const float4*)(Wvp + (jb + 3) * 64 + r);
      c0 += sp4.x * w0.x + sp4.y * w0.y + sp4.z * w0.z + sp4.w * w0.w;
      c1 += sp4.x * w1.x + sp4.y * w1.y + sp4.z * w1.z + sp4.w * w1.w;
      c2 += sp4.x * w2.x + sp4.y * w2.y + sp4.z * w2.z + sp4.w * w2.w;
      c3 += sp4.x * w3.x + sp4.y * w3.y + sp4.z * w3.z + sp4.w * w3.w;
    }
    int s = q0 + q;
    const float* lrow = ctxl + (size_t)(bh * 2048 + s) * 64 + jb;
    float4 lv = *(const float4*)lrow;
    short4 o;
    o.x = f2bf(0.5f * (lv.x + c0));
    o.y = f2bf(0.5f * (lv.y + c1));
    o.z = f2bf(0.5f * (lv.z + c2));
    o.w = f2bf(0.5f * (lv.w + c3));
    *(short4*)(ctxcb + (size_t)(b * 2048 + s) * 512 + hh * 64 + jb) = o;
  }
}

// ---------------------------------------------------------------------------
// MFMA Wo gemm: 64-row blocks (grid 64x8 = 512 blocks, 2/CU). Wave = 16 rows.
// ---------------------------------------------------------------------------
__global__ __launch_bounds__(256, 4) void gemm_wo(
    const short* __restrict__ Abf, const short* __restrict__ Wbf,
    const float* __restrict__ bo, const float* __restrict__ h,
    float* __restrict__ outp) {
  int m0 = blockIdx.x * 64;
  int n0 = blockIdx.y * 64;
  int tid = threadIdx.x;
  int wvv = tid >> 6, lane = tid & 63;
  int quad = lane >> 4, l16 = lane & 15;
  int mw = m0 + wvv * 16;
  const short* ap = Abf + (size_t)(mw + l16) * 512 + quad * 8;
  const short* bp = Wbf + (size_t)(n0 + l16) * 512 + quad * 8;
  f32x4 acc[4] = {};
  bf16x8 cA = *(const bf16x8*)ap;
  bf16x8 cB0 = *(const bf16x8*)(bp + 0 * 16 * 512);
  bf16x8 cB1 = *(const bf16x8*)(bp + 1 * 16 * 512);
  bf16x8 cB2 = *(const bf16x8*)(bp + 2 * 16 * 512);
  bf16x8 cB3 = *(const bf16x8*)(bp + 3 * 16 * 512);
#pragma unroll 1
  for (int ks = 0; ks < 16; ks++) {
    int offn = (ks + 1 < 16 ? ks + 1 : 15) * 32;
    bf16x8 nA = *(const bf16x8*)(ap + offn);
    bf16x8 nB0 = *(const bf16x8*)(bp + 0 * 16 * 512 + offn);
    bf16x8 nB1 = *(const bf16x8*)(bp + 1 * 16 * 512 + offn);
    bf16x8 nB2 = *(const bf16x8*)(bp + 2 * 16 * 512 + offn);
    bf16x8 nB3 = *(const bf16x8*)(bp + 3 * 16 * 512 + offn);
    acc[0] = __builtin_amdgcn_mfma_f32_16x16x32_bf16(cA, cB0, acc[0], 0, 0, 0);
    acc[1] = __builtin_amdgcn_mfma_f32_16x16x32_bf16(cA, cB1, acc[1], 0, 0, 0);
    acc[2] = __builtin_amdgcn_mfma_f32_16x16x32_bf16(cA, cB2, acc[2], 0, 0, 0);
    acc[3] = __builtin_amdgcn_mfma_f32_16x16x32_bf16(cA, cB3, acc[3], 0, 0, 0);
    cA = nA;
    cB0 = nB0; cB1 = nB1; cB2 = nB2; cB3 = nB3;
  }
#pragma unroll
  for (int r = 0; r < 4; r++) {
    int m = mw + quad * 4 + r;
#pragma unroll
    for (int t = 0; t < 4; t++) {
      int n = n0 + t * 16 + l16;
      outp[(size_t)m * 512 + n] =
          acc[t][r] + bo[n] + h[(size_t)m * 512 + n];
    }
  }
}

// ---------------------------------------------------------------------------
// layernorm in place on d_out, one block per row
// ---------------------------------------------------------------------------
__global__ __launch_bounds__(256) void ln_kernel(float* __restrict__ o,
                                                 const float* __restrict__ g,
                                                 const float* __restrict__ bb) {
  int row = blockIdx.x;
  int tid = threadIdx.x;
  float v0 = o[row * 512 + tid];
  float v1 = o[row * 512 + 256 + tid];
  float s = v0 + v1;
  float s2 = v0 * v0 + v1 * v1;
#pragma unroll
  for (int off = 1; off < 64; off <<= 1) {
    s += __shfl_xor(s, off);
    s2 += __shfl_xor(s2, off);
  }
  __shared__ float ps[4], ps2[4];
  int w = tid >> 6;
  if ((tid & 63) == 0) { ps[w] = s; ps2[w] = s2; }
  __syncthreads();
  float S = ps[0] + ps[1] + ps[2] + ps[3];
  float S2 = ps2[0] + ps2[1] + ps2[2] + ps2[3];
  float mu = S * (1.f / 512.f);
  float var = S2 * (1.f / 512.f) - mu * mu;
  float inv = rsqrtf(var + 1e-5f);
  o[row * 512 + tid] = (v0 - mu) * inv * g[tid] + bb[tid];
  o[row * 512 + 256 + tid] = (v1 - mu) * inv * g[tid + 256] + bb[tid + 256];
}

// ---------------------------------------------------------------------------
extern "C" void kernel_launch(void* const* d_in, const int* in_sizes, int n_in,
                              void* d_out, int out_size, void* d_ws,
                              size_t ws_size, hipStream_t stream) {
  const float* x   = (const float*)d_in[0];
  const float* w1  = (const float*)d_in[1];
  const float* b1  = (const float*)d_in[2];
  const float* w2  = (const float*)d_in[3];
  const float* b2  = (const float*)d_in[4];
  const float* w3  = (const float*)d_in[5];
  const float* b3  = (const float*)d_in[6];
  const float* Wq  = (const float*)d_in[7];
  const float* bq  = (const float*)d_in[8];
  const float* Wk  = (const float*)d_in[9];
  const float* bk  = (const float*)d_in[10];
  const float* Wv  = (const float*)d_in[11];
  const float* bv  = (const float*)d_in[12];
  const float* Wkp = (const float*)d_in[13];
  const float* bkp = (const float*)d_in[14];
  const float* Wvp = (const float*)d_in[15];
  const float* bvp = (const float*)d_in[16];
  const float* Wo  = (const float*)d_in[17];
  const float* bo  = (const float*)d_in[18];
  const float* lng = (const float*)d_in[19];
  const float* lnb = (const float*)d_in[20];

  float* p = (float*)d_ws;
  short* Wallbf = (short*)p;  p += 786432;
  float* ball   = p;          p += 2048;
  short* Wobf   = (short*)p;  p += 262144;
  short* Wkpbf  = (short*)p;  p += 4096;
  short* Wvpbf  = (short*)p;  p += 4096;
  float* h      = p;          p += 2097152;
  short* hbf    = (short*)p;  p += 1048576;
  short* Qh     = (short*)p;  p += 1048576;
  short* Kh     = (short*)p;  p += 1048576;
  short* Vh     = (short*)p;  p += 1048576;
  short* Kph    = (short*)p;  p += 1048576;
  float* Vp     = p;          p += 2097152;
  float* ctxl   = p;          p += 2097152;
  short* ctxcb  = (short*)p;  p += 1048576;
  float* outF   = (float*)d_out;

  prep_kernel<<<512, 256, 0, stream>>>(Wq, Wk, Wv, bq, bk, bv, Wo, Wkp, Wvp,
                                       Wallbf, ball, Wobf, Wkpbf, Wvpbf);
  conv_kernel<<<1024, 256, 0, stream>>>(x, w1, b1, w2, b2, w3, b3, h, hbf);
  {
    dim3 g(64, 24);
    gemm_qkv<<<g, 256, 0, stream>>>(hbf, Wallbf, ball, Qh, Kh, Vh);
  }
  kpvp_kernel<<<512, 256, 0, stream>>>(Kh, Vh, Wkpbf, bkp, Wvpbf, bvp, Kph,
                                       Vp);
  local_attn<<<512, 256, 0, stream>>>(Qh, Kh, Vh, ctxl);
  global_attn<<<2048, 256, 0, stream>>>(Qh, Kph, Vp, Wvp, bvp, ctxl, ctxcb);
  {
    dim3 g(64, 8);
    gemm_wo<<<g, 256, 0, stream>>>(ctxcb, Wobf, bo, h, outF);
  }
  ln_kernel<<<4096, 256, 0, stream>>>(outF, lng, lnb);
}

// Round 15
// 355.439 us; speedup vs baseline: 1.1699x; 1.1699x over previous
//
#include <hip/hip_runtime.h>
#include <hip/hip_bf16.h>

#define BB 2
#define SS 2048
#define INC 64
#define HIDN 512
#define NHH 8
#define HDD 64

typedef __attribute__((ext_vector_type(8))) short bf16x8;
typedef __attribute__((ext_vector_type(4))) float f32x4;

__device__ __forceinline__ short f2bf(float f) {
  union { __hip_bfloat16 h; short s; } u;
  u.h = __float2bfloat16(f);
  return u.s;
}
__device__ __forceinline__ float bf2f(short s) {
  return __uint_as_float(((unsigned)(unsigned short)s) << 16);
}

// ---------------------------------------------------------------------------
// prep: bf16 weights. Wallbf = concat(Wq,Wk,Wv) rows (n,k) = 1536x512;
// Wobf = Wo (n,k); Wkpbf/Wvpbf = 64x64; ball = concat qkv biases.
// ---------------------------------------------------------------------------
__global__ __launch_bounds__(256) void prep_kernel(
    const float* __restrict__ Wq, const float* __restrict__ Wk_,
    const float* __restrict__ Wv_, const float* __restrict__ bq,
    const float* __restrict__ bk_, const float* __restrict__ bv_,
    const float* __restrict__ Wo, const float* __restrict__ Wkp,
    const float* __restrict__ Wvp, short* __restrict__ Wallbf,
    float* __restrict__ ball, short* __restrict__ Wobf,
    short* __restrict__ Wkpbf, short* __restrict__ Wvpbf) {
  int i0 = blockIdx.x * 256 + threadIdx.x;
  int stride = gridDim.x * 256;
  for (int idx = i0; idx < 786432; idx += stride) {
    float v;
    if (idx < 262144)      v = Wq[idx];
    else if (idx < 524288) v = Wk_[idx - 262144];
    else                   v = Wv_[idx - 524288];
    Wallbf[idx] = f2bf(v);
  }
  for (int idx = i0; idx < 262144; idx += stride) Wobf[idx] = f2bf(Wo[idx]);
  for (int idx = i0; idx < 4096; idx += stride) {
    Wkpbf[idx] = f2bf(Wkp[idx]);
    Wvpbf[idx] = f2bf(Wvp[idx]);
  }
  if (i0 < 1536) {
    float v;
    if (i0 < 512)       v = bq[i0];
    else if (i0 < 1024) v = bk_[i0 - 512];
    else                v = bv_[i0 - 1024];
    ball[i0] = v;
  }
}

// ---------------------------------------------------------------------------
// conv: h[b,s,c] = relu(conv{1,2,3}(x)); writes bf16 hbf ONLY (fp32 h
// eliminated — residual downstream uses bf16).  TS=8 (R13 config).
// ---------------------------------------------------------------------------
template <int KW, int OFF>
__device__ __forceinline__ void conv_channel(const float* __restrict__ w,
                                             const float* xs, float bias,
                                             float acc[8]) {
#pragma unroll
  for (int i = 0; i < 8; i++) acc[i] = bias;
#pragma unroll 4
  for (int ci = 0; ci < 64; ci++) {
    float xv[8 + KW - 1];
#pragma unroll
    for (int r = 0; r < 8 + KW - 1; r++) xv[r] = xs[(r + OFF) * 64 + ci];
#pragma unroll
    for (int k = 0; k < KW; k++) {
      float wv = w[ci * KW + k];
#pragma unroll
      for (int i = 0; i < 8; i++) acc[i] += xv[i + k] * wv;
    }
  }
}

__global__ __launch_bounds__(256) void conv_kernel(
    const float* __restrict__ x, const float* __restrict__ w1,
    const float* __restrict__ b1, const float* __restrict__ w2,
    const float* __restrict__ b2, const float* __restrict__ w3,
    const float* __restrict__ b3, short* __restrict__ hbf) {
  const int TS = 8;
  int blk = blockIdx.x;                 // 512 blocks
  int b = blk / (SS / TS);
  int s0 = (blk % (SS / TS)) * TS;
  __shared__ float xs[(TS + 6) * 64];
  int tid = threadIdx.x;
  for (int i = tid; i < (TS + 6) * 64; i += 256) {
    int row = i >> 6, ci = i & 63;
    int sgl = s0 + row - 3;
    xs[i] = (sgl >= 0 && sgl < SS) ? x[(b * SS + sgl) * 64 + ci] : 0.f;
  }
  __syncthreads();
  for (int c = tid; c < 512; c += 256) {
    float acc[8];
    if (c < 171) {
      conv_channel<3, 2>(w1 + c * (64 * 3), xs, b1[c], acc);
    } else if (c < 342) {
      conv_channel<5, 1>(w2 + (c - 171) * (64 * 5), xs, b2[c - 171], acc);
    } else {
      conv_channel<7, 0>(w3 + (c - 342) * (64 * 7), xs, b3[c - 342], acc);
    }
#pragma unroll
    for (int i = 0; i < 8; i++) {
      float v = fmaxf(acc[i], 0.f);
      hbf[(b * SS + s0 + i) * 512 + c] = f2bf(v);
    }
  }
}

// ---------------------------------------------------------------------------
// MFMA QKV gemm (R13 config): 128-row blocks, wave = 32 rows x 64 cols,
// double-buffered register prefetch, launch_bounds(256,4).
// ---------------------------------------------------------------------------
__global__ __launch_bounds__(256, 4) void gemm_qkv(
    const short* __restrict__ Abf, const short* __restrict__ Wbf,
    const float* __restrict__ bias, short* __restrict__ Qh,
    short* __restrict__ Kh, short* __restrict__ Vh) {
  int m0 = blockIdx.x * 128;
  int n0 = blockIdx.y * 64;
  int tid = threadIdx.x;
  int wvv = tid >> 6, lane = tid & 63;
  int quad = lane >> 4, l16 = lane & 15;
  int mw = m0 + wvv * 32;
  const short* ap0 = Abf + (size_t)(mw + l16) * 512 + quad * 8;
  const short* ap1 = ap0 + 16 * 512;
  const short* bp = Wbf + (size_t)(n0 + l16) * 512 + quad * 8;
  f32x4 acc[2][4] = {};
  bf16x8 cA0 = *(const bf16x8*)ap0;
  bf16x8 cA1 = *(const bf16x8*)ap1;
  bf16x8 cB0 = *(const bf16x8*)(bp + 0 * 16 * 512);
  bf16x8 cB1 = *(const bf16x8*)(bp + 1 * 16 * 512);
  bf16x8 cB2 = *(const bf16x8*)(bp + 2 * 16 * 512);
  bf16x8 cB3 = *(const bf16x8*)(bp + 3 * 16 * 512);
#pragma unroll 1
  for (int ks = 0; ks < 16; ks++) {
    int offn = (ks + 1 < 16 ? ks + 1 : 15) * 32;
    bf16x8 nA0 = *(const bf16x8*)(ap0 + offn);
    bf16x8 nA1 = *(const bf16x8*)(ap1 + offn);
    bf16x8 nB0 = *(const bf16x8*)(bp + 0 * 16 * 512 + offn);
    bf16x8 nB1 = *(const bf16x8*)(bp + 1 * 16 * 512 + offn);
    bf16x8 nB2 = *(const bf16x8*)(bp + 2 * 16 * 512 + offn);
    bf16x8 nB3 = *(const bf16x8*)(bp + 3 * 16 * 512 + offn);
    acc[0][0] = __builtin_amdgcn_mfma_f32_16x16x32_bf16(cA0, cB0, acc[0][0], 0, 0, 0);
    acc[1][0] = __builtin_amdgcn_mfma_f32_16x16x32_bf16(cA1, cB0, acc[1][0], 0, 0, 0);
    acc[0][1] = __builtin_amdgcn_mfma_f32_16x16x32_bf16(cA0, cB1, acc[0][1], 0, 0, 0);
    acc[1][1] = __builtin_amdgcn_mfma_f32_16x16x32_bf16(cA1, cB1, acc[1][1], 0, 0, 0);
    acc[0][2] = __builtin_amdgcn_mfma_f32_16x16x32_bf16(cA0, cB2, acc[0][2], 0, 0, 0);
    acc[1][2] = __builtin_amdgcn_mfma_f32_16x16x32_bf16(cA1, cB2, acc[1][2], 0, 0, 0);
    acc[0][3] = __builtin_amdgcn_mfma_f32_16x16x32_bf16(cA0, cB3, acc[0][3], 0, 0, 0);
    acc[1][3] = __builtin_amdgcn_mfma_f32_16x16x32_bf16(cA1, cB3, acc[1][3], 0, 0, 0);
    cA0 = nA0; cA1 = nA1;
    cB0 = nB0; cB1 = nB1; cB2 = nB2; cB3 = nB3;
  }
  int which = n0 >> 9;
  int head = (n0 >> 6) & 7;
  short* dst = which == 0 ? Qh : (which == 1 ? Kh : Vh);
  float scale = which == 0 ? 0.125f : 1.0f;
#pragma unroll
  for (int mt = 0; mt < 2; mt++) {
#pragma unroll
    for (int r = 0; r < 4; r++) {
      int m = mw + mt * 16 + quad * 4 + r;
      int bb = m >> 11, s = m & 2047;
      size_t rowoff = ((size_t)(bb * 8 + head) * 2048 + s) * 64;
#pragma unroll
      for (int t = 0; t < 4; t++) {
        int hd = t * 16 + l16;
        float v = acc[mt][t][r] + bias[n0 + hd];
        dst[rowoff + hd] = f2bf(v * scale);
      }
    }
  }
}

// ---------------------------------------------------------------------------
// kpvp via MFMA (R13 config): 128-row blocks, wave = 32 rows.
// ---------------------------------------------------------------------------
__global__ __launch_bounds__(256, 4) void kpvp_kernel(
    const short* __restrict__ Kh, const short* __restrict__ Vh,
    const short* __restrict__ Wkpbf, const float* __restrict__ bkp,
    const short* __restrict__ Wvpbf, const float* __restrict__ bvp,
    short* __restrict__ Kph, float* __restrict__ Vp) {
  int m0 = blockIdx.x * 128;            // 256 blocks over 32768 rows
  int tid = threadIdx.x;
  int wvv = tid >> 6, lane = tid & 63;
  int quad = lane >> 4, l16 = lane & 15;
  int mw = m0 + wvv * 32;
  {
    const short* ap0 = Kh + (size_t)(mw + l16) * 64 + quad * 8;
    const short* ap1 = ap0 + 16 * 64;
    const short* bp = Wkpbf + l16 * 64 + quad * 8;
    bf16x8 A00 = *(const bf16x8*)ap0, A01 = *(const bf16x8*)(ap0 + 32);
    bf16x8 A10 = *(const bf16x8*)ap1, A11 = *(const bf16x8*)(ap1 + 32);
    f32x4 acc[2][4] = {};
#pragma unroll
    for (int t = 0; t < 4; t++) {
      bf16x8 B0 = *(const bf16x8*)(bp + t * 16 * 64);
      bf16x8 B1 = *(const bf16x8*)(bp + t * 16 * 64 + 32);
      acc[0][t] = __builtin_amdgcn_mfma_f32_16x16x32_bf16(A00, B0, acc[0][t], 0, 0, 0);
      acc[0][t] = __builtin_amdgcn_mfma_f32_16x16x32_bf16(A01, B1, acc[0][t], 0, 0, 0);
      acc[1][t] = __builtin_amdgcn_mfma_f32_16x16x32_bf16(A10, B0, acc[1][t], 0, 0, 0);
      acc[1][t] = __builtin_amdgcn_mfma_f32_16x16x32_bf16(A11, B1, acc[1][t], 0, 0, 0);
    }
#pragma unroll
    for (int mt = 0; mt < 2; mt++)
#pragma unroll
      for (int r = 0; r < 4; r++) {
        int m = mw + mt * 16 + quad * 4 + r;
#pragma unroll
        for (int t = 0; t < 4; t++) {
          int n = t * 16 + l16;
          Kph[(size_t)m * 64 + n] = f2bf(acc[mt][t][r] + bkp[n]);
        }
      }
  }
  {
    const short* ap0 = Vh + (size_t)(mw + l16) * 64 + quad * 8;
    const short* ap1 = ap0 + 16 * 64;
    const short* bp = Wvpbf + l16 * 64 + quad * 8;
    bf16x8 A00 = *(const bf16x8*)ap0, A01 = *(const bf16x8*)(ap0 + 32);
    bf16x8 A10 = *(const bf16x8*)ap1, A11 = *(const bf16x8*)(ap1 + 32);
    f32x4 acc[2][4] = {};
#pragma unroll
    for (int t = 0; t < 4; t++) {
      bf16x8 B0 = *(const bf16x8*)(bp + t * 16 * 64);
      bf16x8 B1 = *(const bf16x8*)(bp + t * 16 * 64 + 32);
      acc[0][t] = __builtin_amdgcn_mfma_f32_16x16x32_bf16(A00, B0, acc[0][t], 0, 0, 0);
      acc[0][t] = __builtin_amdgcn_mfma_f32_16x16x32_bf16(A01, B1, acc[0][t], 0, 0, 0);
      acc[1][t] = __builtin_amdgcn_mfma_f32_16x16x32_bf16(A10, B0, acc[1][t], 0, 0, 0);
      acc[1][t] = __builtin_amdgcn_mfma_f32_16x16x32_bf16(A11, B1, acc[1][t], 0, 0, 0);
    }
#pragma unroll
    for (int mt = 0; mt < 2; mt++)
#pragma unroll
      for (int r = 0; r < 4; r++) {
        int m = mw + mt * 16 + quad * 4 + r;
#pragma unroll
        for (int t = 0; t < 4; t++) {
          int n = t * 16 + l16;
          Vp[(size_t)m * 64 + n] = acc[mt][t][r] + bvp[n];
        }
      }
  }
}

// ---------------------------------------------------------------------------
// local windowed attention, MFMA on bf16: one wave per 16-query tile.
// ---------------------------------------------------------------------------
__global__ __launch_bounds__(256) void local_attn(
    const short* __restrict__ Qh, const short* __restrict__ Kh,
    const short* __restrict__ Vh, float* __restrict__ ctxl) {
  int wv = threadIdx.x >> 6;
  int tile = blockIdx.x * 4 + wv;       // 0..2047
  int bh = tile >> 7;
  int q0 = (tile & 127) * 16;
  int lane = threadIdx.x & 63;
  int quad = lane >> 4, l16 = lane & 15;

  __shared__ float Sloc[4][2][16][17];
  __shared__ float wloc[4][16][8];

  const short* qbase = Qh + (size_t)(bh * 2048 + q0 + l16) * 64 + quad * 8;
  bf16x8 a0 = *(const bf16x8*)qbase;
  bf16x8 a1 = *(const bf16x8*)(qbase + 32);

  int k0a = min(max(q0 - 2 + l16, 0), 2047);
  int k1a = min(q0 + 6 + l16, 2047);
  const short* kb0 = Kh + (size_t)(bh * 2048 + k0a) * 64 + quad * 8;
  const short* kb1 = Kh + (size_t)(bh * 2048 + k1a) * 64 + quad * 8;
  bf16x8 B00 = *(const bf16x8*)kb0;
  bf16x8 B01 = *(const bf16x8*)(kb0 + 32);
  bf16x8 B10 = *(const bf16x8*)kb1;
  bf16x8 B11 = *(const bf16x8*)(kb1 + 32);
  f32x4 C0 = {0.f, 0.f, 0.f, 0.f};
  f32x4 C1 = {0.f, 0.f, 0.f, 0.f};
  C0 = __builtin_amdgcn_mfma_f32_16x16x32_bf16(a0, B00, C0, 0, 0, 0);
  C0 = __builtin_amdgcn_mfma_f32_16x16x32_bf16(a1, B01, C0, 0, 0, 0);
  C1 = __builtin_amdgcn_mfma_f32_16x16x32_bf16(a0, B10, C1, 0, 0, 0);
  C1 = __builtin_amdgcn_mfma_f32_16x16x32_bf16(a1, B11, C1, 0, 0, 0);
#pragma unroll
  for (int r = 0; r < 4; r++) {
    Sloc[wv][0][quad * 4 + r][l16] = C0[r];
    Sloc[wv][1][quad * 4 + r][l16] = C1[r];
  }
  __builtin_amdgcn_wave_barrier();
  if (lane < 16) {
    int q = lane;
    float sc[5];
    bool ok[5];
#pragma unroll
    for (int j = 0; j < 5; j++) {
      int offq = q + j - 2;
      int sg = q0 + offq;
      ok[j] = (sg >= 0 && sg < SS);
      int t = offq <= 13 ? 0 : 1;
      int col = t ? offq - 6 : offq + 2;
      sc[j] = ok[j] ? Sloc[wv][t][q][col] : -3.0e38f;
    }
    float m = -3.0e38f;
#pragma unroll
    for (int j = 0; j < 5; j++) m = fmaxf(m, sc[j]);
    float e[5], l = 0.f;
#pragma unroll
    for (int j = 0; j < 5; j++) {
      e[j] = ok[j] ? __expf(sc[j] - m) : 0.f;
      l += e[j];
    }
    float inv = 1.f / l;
#pragma unroll
    for (int j = 0; j < 5; j++) wloc[wv][q][j] = e[j] * inv;
  }
  __builtin_amdgcn_wave_barrier();
  {
    int q = lane >> 2, jb = (lane & 3) * 16;
    int s = q0 + q;
    float acc[16] = {};
#pragma unroll
    for (int j = 0; j < 5; j++) {
      int sg = s + j - 2;
      if (sg >= 0 && sg < SS) {
        float w = wloc[wv][q][j];
        const short* vr = Vh + (size_t)(bh * 2048 + sg) * 64 + jb;
#pragma unroll
        for (int u = 0; u < 16; u += 4) {
          short4 v4 = *(const short4*)(vr + u);
          acc[u + 0] += w * bf2f(v4.x);
          acc[u + 1] += w * bf2f(v4.y);
          acc[u + 2] += w * bf2f(v4.z);
          acc[u + 3] += w * bf2f(v4.w);
        }
      }
    }
    float* orow = ctxl + (size_t)(bh * 2048 + s) * 64 + jb;
#pragma unroll
    for (int u = 0; u < 16; u += 4)
      *(float4*)(orow + u) =
          make_float4(acc[u], acc[u + 1], acc[u + 2], acc[u + 3]);
  }
}

// ---------------------------------------------------------------------------
// global sparse attention — R13 exact: single-pass depth-8 insert, 2-wide
// ILP, launch_bounds(256,4).
// ---------------------------------------------------------------------------
__global__ __launch_bounds__(256, 4) void global_attn(
    const short* __restrict__ Qh, const short* __restrict__ Kph,
    const float* __restrict__ Vp, const float* __restrict__ Wvp,
    const float* __restrict__ bvp, const float* __restrict__ ctxl,
    short* __restrict__ ctxcb) {
  int wid = blockIdx.x;                // 2048
  int bh = wid >> 7;
  int q0 = (wid & 127) * 16;
  int b = bh >> 3, hh = bh & 7;
  int tid = threadIdx.x;
  int wv = tid >> 6;
  int lane = tid & 63;
  int quad = lane >> 4, l16 = lane & 15;

  __shared__ unsigned mer[4][16][17];
  __shared__ float tw[16][17];
  __shared__ int   tix[16][17];
  __shared__ float spr[16][68];

  const short* qbase = Qh + (size_t)(bh * 2048 + q0 + l16) * 64 + quad * 8;
  bf16x8 a0 = *(const bf16x8*)qbase;
  bf16x8 a1 = *(const bf16x8*)(qbase + 32);

  const short* kbase =
      Kph + (size_t)(bh * 2048 + wv * 512 + l16) * 64 + quad * 8;

  unsigned e0[8], e1[8], e2[8], e3[8];
#pragma unroll
  for (int j = 0; j < 8; j++) { e0[j] = 0; e1[j] = 0; e2[j] = 0; e3[j] = 0; }

  auto insert8 = [&](unsigned (&er)[8], unsigned cand) {
    unsigned p = cand;
#pragma unroll
    for (int j = 0; j < 8; j++) {
      unsigned cur = er[j];
      unsigned hi = cur > p ? cur : p;   // v_max_u32
      p = cur > p ? p : cur;             // v_min_u32
      er[j] = hi;
    }
  };
  auto mkcand = [&](float s, int idxr) -> unsigned {
    unsigned u = __float_as_uint(s);
    u ^= ((unsigned)((int)u >> 31)) | 0x80000000u;
    return (u & 0xFFFFF800u) | (unsigned)idxr;
  };

  int idxbase = 2047 - (wv * 512 + l16);
  {
    bf16x8 B00 = *(const bf16x8*)kbase;
    bf16x8 B01 = *(const bf16x8*)(kbase + 32);
    bf16x8 B10 = *(const bf16x8*)(kbase + 1024);
    bf16x8 B11 = *(const bf16x8*)(kbase + 1024 + 32);
#pragma unroll 1
    for (int g = 0; g < 32; g += 2) {
      int g2 = (g + 2 < 32) ? g + 2 : 30;
      int g3 = (g + 3 < 32) ? g + 3 : 31;
      bf16x8 P00 = *(const bf16x8*)(kbase + g2 * 1024);
      bf16x8 P01 = *(const bf16x8*)(kbase + g2 * 1024 + 32);
      bf16x8 P10 = *(const bf16x8*)(kbase + g3 * 1024);
      bf16x8 P11 = *(const bf16x8*)(kbase + g3 * 1024 + 32);
      f32x4 C0 = {0.f, 0.f, 0.f, 0.f};
      f32x4 C1 = {0.f, 0.f, 0.f, 0.f};
      C0 = __builtin_amdgcn_mfma_f32_16x16x32_bf16(a0, B00, C0, 0, 0, 0);
      C0 = __builtin_amdgcn_mfma_f32_16x16x32_bf16(a1, B01, C0, 0, 0, 0);
      C1 = __builtin_amdgcn_mfma_f32_16x16x32_bf16(a0, B10, C1, 0, 0, 0);
      C1 = __builtin_amdgcn_mfma_f32_16x16x32_bf16(a1, B11, C1, 0, 0, 0);
      int idxr0 = idxbase - (g << 4);
      int idxr1 = idxbase - ((g + 1) << 4);
      insert8(e0, mkcand(C0[0], idxr0));
      insert8(e1, mkcand(C0[1], idxr0));
      insert8(e2, mkcand(C0[2], idxr0));
      insert8(e3, mkcand(C0[3], idxr0));
      insert8(e0, mkcand(C1[0], idxr1));
      insert8(e1, mkcand(C1[1], idxr1));
      insert8(e2, mkcand(C1[2], idxr1));
      insert8(e3, mkcand(C1[3], idxr1));
      B00 = P00; B01 = P01; B10 = P10; B11 = P11;
    }
  }

  auto wmerge = [&](unsigned (&er)[8], int r) {
#pragma unroll
    for (int t = 0; t < 16; t++) {
      unsigned w = er[0];
#pragma unroll
      for (int mm = 1; mm <= 8; mm <<= 1) {
        unsigned o = (unsigned)__shfl_xor((int)w, mm);
        w = w > o ? w : o;
      }
      if (er[0] == w) {
#pragma unroll
        for (int j = 0; j < 7; j++) er[j] = er[j + 1];
        er[7] = 0;
      }
      if (l16 == r) mer[wv][quad * 4 + r][t] = w;
    }
  };
  wmerge(e0, 0);
  wmerge(e1, 1);
  wmerge(e2, 2);
  wmerge(e3, 3);
  __syncthreads();

  if (tid < 16) {
    int q = tid;
    unsigned h0 = mer[0][q][0], h1 = mer[1][q][0];
    unsigned h2 = mer[2][q][0], h3 = mer[3][q][0];
    int p0 = 1, p1 = 1, p2 = 1, p3 = 1;
    float mval = 0.f, lsum = 0.f;
    float ev[16];
    int kit[16];
#pragma unroll
    for (int t = 0; t < 16; t++) {
      unsigned w01 = h0 > h1 ? h0 : h1;
      unsigned w23 = h2 > h3 ? h2 : h3;
      unsigned w = w01 > w23 ? w01 : w23;
      if (w == h0)      { h0 = p0 < 16 ? mer[0][q][p0] : 0u; p0++; }
      else if (w == h1) { h1 = p1 < 16 ? mer[1][q][p1] : 0u; p1++; }
      else if (w == h2) { h2 = p2 < 16 ? mer[2][q][p2] : 0u; p2++; }
      else              { h3 = p3 < 16 ? mer[3][q][p3] : 0u; p3++; }
      unsigned wvv = w & 0xFFFFF800u;
      unsigned uu = (w & 0x80000000u) ? (wvv ^ 0x80000000u) : ~wvv;
      float sv = (w == 0u) ? -1.0e30f : __uint_as_float(uu);
      int ki = 2047 - (int)(w & 0x7FFu);
      if (t == 0) mval = sv;
      float ex = __expf(sv - mval);
      lsum += ex;
      ev[t] = ex;
      kit[t] = ki;
    }
    float inv = 1.f / lsum;
#pragma unroll
    for (int j = 0; j < 16; j++) {
      tw[q][j] = ev[j] * inv;
      tix[q][j] = kit[j];
    }
  }
  __syncthreads();

  {
    int q = tid >> 4, rl = (tid & 15) * 4;
    float ax = 0.f, ay = 0.f, az = 0.f, aw = 0.f;
#pragma unroll 4
    for (int j = 0; j < 16; j++) {
      float w = tw[q][j];
      const float* vrow = Vp + (size_t)(bh * 2048 + tix[q][j]) * 64 + rl;
      float4 v = *(const float4*)vrow;
      ax += w * v.x; ay += w * v.y; az += w * v.z; aw += w * v.w;
    }
    *(float4*)&spr[q][rl] = make_float4(ax, ay, az, aw);
  }
  __syncthreads();

  {
    int q = tid >> 4, jb = (tid & 15) * 4;
    float c0 = bvp[jb], c1 = bvp[jb + 1], c2 = bvp[jb + 2], c3 = bvp[jb + 3];
    for (int r = 0; r < 64; r += 4) {
      float4 sp4 = *(const float4*)&spr[q][r];
      float4 w0 = *(const float4*)(Wvp + (jb + 0) * 64 + r);
      float4 w1 = *(const float4*)(Wvp + (jb + 1) * 64 + r);
      float4 w2 = *(const float4*)(Wvp + (jb + 2) * 64 + r);
      float4 w3 = *(const float4*)(Wvp + (jb + 3) * 64 + r);
      c0 += sp4.x * w0.x + sp4.y * w0.y + sp4.z * w0.z + sp4.w * w0.w;
      c1 += sp4.x * w1.x + sp4.y * w1.y + sp4.z * w1.z + sp4.w * w1.w;
      c2 += sp4.x * w2.x + sp4.y * w2.y + sp4.z * w2.z + sp4.w * w2.w;
      c3 += sp4.x * w3.x + sp4.y * w3.y + sp4.z * w3.z + sp4.w * w3.w;
    }
    int s = q0 + q;
    const float* lrow = ctxl + (size_t)(bh * 2048 + s) * 64 + jb;
    float4 lv = *(const float4*)lrow;
    short4 o;
    o.x = f2bf(0.5f * (lv.x + c0));
    o.y = f2bf(0.5f * (lv.y + c1));
    o.z = f2bf(0.5f * (lv.z + c2));
    o.w = f2bf(0.5f * (lv.w + c3));
    *(short4*)(ctxcb + (size_t)(b * 2048 + s) * 512 + hh * 64 + jb) = o;
  }
}

// ---------------------------------------------------------------------------
// MFMA Wo gemm (R13 config): 128-row blocks, wave = 32 rows. Residual from
// bf16 hbf (fp32 h eliminated).
// ---------------------------------------------------------------------------
__global__ __launch_bounds__(256, 4) void gemm_wo(
    const short* __restrict__ Abf, const short* __restrict__ Wbf,
    const float* __restrict__ bo, const short* __restrict__ hbf,
    float* __restrict__ outp) {
  int m0 = blockIdx.x * 128;
  int n0 = blockIdx.y * 64;
  int tid = threadIdx.x;
  int wvv = tid >> 6, lane = tid & 63;
  int quad = lane >> 4, l16 = lane & 15;
  int mw = m0 + wvv * 32;
  const short* ap0 = Abf + (size_t)(mw + l16) * 512 + quad * 8;
  const short* ap1 = ap0 + 16 * 512;
  const short* bp = Wbf + (size_t)(n0 + l16) * 512 + quad * 8;
  f32x4 acc[2][4] = {};
  bf16x8 cA0 = *(const bf16x8*)ap0;
  bf16x8 cA1 = *(const bf16x8*)ap1;
  bf16x8 cB0 = *(const bf16x8*)(bp + 0 * 16 * 512);
  bf16x8 cB1 = *(const bf16x8*)(bp + 1 * 16 * 512);
  bf16x8 cB2 = *(const bf16x8*)(bp + 2 * 16 * 512);
  bf16x8 cB3 = *(const bf16x8*)(bp + 3 * 16 * 512);
#pragma unroll 1
  for (int ks = 0; ks < 16; ks++) {
    int offn = (ks + 1 < 16 ? ks + 1 : 15) * 32;
    bf16x8 nA0 = *(const bf16x8*)(ap0 + offn);
    bf16x8 nA1 = *(const bf16x8*)(ap1 + offn);
    bf16x8 nB0 = *(const bf16x8*)(bp + 0 * 16 * 512 + offn);
    bf16x8 nB1 = *(const bf16x8*)(bp + 1 * 16 * 512 + offn);
    bf16x8 nB2 = *(const bf16x8*)(bp + 2 * 16 * 512 + offn);
    bf16x8 nB3 = *(const bf16x8*)(bp + 3 * 16 * 512 + offn);
    acc[0][0] = __builtin_amdgcn_mfma_f32_16x16x32_bf16(cA0, cB0, acc[0][0], 0, 0, 0);
    acc[1][0] = __builtin_amdgcn_mfma_f32_16x16x32_bf16(cA1, cB0, acc[1][0], 0, 0, 0);
    acc[0][1] = __builtin_amdgcn_mfma_f32_16x16x32_bf16(cA0, cB1, acc[0][1], 0, 0, 0);
    acc[1][1] = __builtin_amdgcn_mfma_f32_16x16x32_bf16(cA1, cB1, acc[1][1], 0, 0, 0);
    acc[0][2] = __builtin_amdgcn_mfma_f32_16x16x32_bf16(cA0, cB2, acc[0][2], 0, 0, 0);
    acc[1][2] = __builtin_amdgcn_mfma_f32_16x16x32_bf16(cA1, cB2, acc[1][2], 0, 0, 0);
    acc[0][3] = __builtin_amdgcn_mfma_f32_16x16x32_bf16(cA0, cB3, acc[0][3], 0, 0, 0);
    acc[1][3] = __builtin_amdgcn_mfma_f32_16x16x32_bf16(cA1, cB3, acc[1][3], 0, 0, 0);
    cA0 = nA0; cA1 = nA1;
    cB0 = nB0; cB1 = nB1; cB2 = nB2; cB3 = nB3;
  }
#pragma unroll
  for (int mt = 0; mt < 2; mt++) {
#pragma unroll
    for (int r = 0; r < 4; r++) {
      int m = mw + mt * 16 + quad * 4 + r;
#pragma unroll
      for (int t = 0; t < 4; t++) {
        int n = n0 + t * 16 + l16;
        outp[(size_t)m * 512 + n] =
            acc[mt][t][r] + bo[n] + bf2f(hbf[(size_t)m * 512 + n]);
      }
    }
  }
}

// ---------------------------------------------------------------------------
// layernorm in place on d_out, one block per row
// ---------------------------------------------------------------------------
__global__ __launch_bounds__(256) void ln_kernel(float* __restrict__ o,
                                                 const float* __restrict__ g,
                                                 const float* __restrict__ bb) {
  int row = blockIdx.x;
  int tid = threadIdx.x;
  float v0 = o[row * 512 + tid];
  float v1 = o[row * 512 + 256 + tid];
  float s = v0 + v1;
  float s2 = v0 * v0 + v1 * v1;
#pragma unroll
  for (int off = 1; off < 64; off <<= 1) {
    s += __shfl_xor(s, off);
    s2 += __shfl_xor(s2, off);
  }
  __shared__ float ps[4], ps2[4];
  int w = tid >> 6;
  if ((tid & 63) == 0) { ps[w] = s; ps2[w] = s2; }
  __syncthreads();
  float S = ps[0] + ps[1] + ps[2] + ps[3];
  float S2 = ps2[0] + ps2[1] + ps2[2] + ps2[3];
  float mu = S * (1.f / 512.f);
  float var = S2 * (1.f / 512.f) - mu * mu;
  float inv = rsqrtf(var + 1e-5f);
  o[row * 512 + tid] = (v0 - mu) * inv * g[tid] + bb[tid];
  o[row * 512 + 256 + tid] = (v1 - mu) * inv * g[tid + 256] + bb[tid + 256];
}

// ---------------------------------------------------------------------------
extern "C" void kernel_launch(void* const* d_in, const int* in_sizes, int n_in,
                              void* d_out, int out_size, void* d_ws,
                              size_t ws_size, hipStream_t stream) {
  const float* x   = (const float*)d_in[0];
  const float* w1  = (const float*)d_in[1];
  const float* b1  = (const float*)d_in[2];
  const float* w2  = (const float*)d_in[3];
  const float* b2  = (const float*)d_in[4];
  const float* w3  = (const float*)d_in[5];
  const float* b3  = (const float*)d_in[6];
  const float* Wq  = (const float*)d_in[7];
  const float* bq  = (const float*)d_in[8];
  const float* Wk  = (const float*)d_in[9];
  const float* bk  = (const float*)d_in[10];
  const float* Wv  = (const float*)d_in[11];
  const float* bv  = (const float*)d_in[12];
  const float* Wkp = (const float*)d_in[13];
  const float* bkp = (const float*)d_in[14];
  const float* Wvp = (const float*)d_in[15];
  const float* bvp = (const float*)d_in[16];
  const float* Wo  = (const float*)d_in[17];
  const float* bo  = (const float*)d_in[18];
  const float* lng = (const float*)d_in[19];
  const float* lnb = (const float*)d_in[20];

  float* p = (float*)d_ws;
  short* Wallbf = (short*)p;  p += 786432;
  float* ball   = p;          p += 2048;
  short* Wobf   = (short*)p;  p += 262144;
  short* Wkpbf  = (short*)p;  p += 4096;
  short* Wvpbf  = (short*)p;  p += 4096;
  short* hbf    = (short*)p;  p += 1048576;
  short* Qh     = (short*)p;  p += 1048576;
  short* Kh     = (short*)p;  p += 1048576;
  short* Vh     = (short*)p;  p += 1048576;
  short* Kph    = (short*)p;  p += 1048576;
  float* Vp     = p;          p += 2097152;
  float* ctxl   = p;          p += 2097152;
  short* ctxcb  = (short*)p;  p += 1048576;
  float* outF   = (float*)d_out;

  prep_kernel<<<512, 256, 0, stream>>>(Wq, Wk, Wv, bq, bk, bv, Wo, Wkp, Wvp,
                                       Wallbf, ball, Wobf, Wkpbf, Wvpbf);
  conv_kernel<<<512, 256, 0, stream>>>(x, w1, b1, w2, b2, w3, b3, hbf);
  {
    dim3 g(32, 24);
    gemm_qkv<<<g, 256, 0, stream>>>(hbf, Wallbf, ball, Qh, Kh, Vh);
  }
  kpvp_kernel<<<256, 256, 0, stream>>>(Kh, Vh, Wkpbf, bkp, Wvpbf, bvp, Kph,
                                       Vp);
  local_attn<<<512, 256, 0, stream>>>(Qh, Kh, Vh, ctxl);
  global_attn<<<2048, 256, 0, stream>>>(Qh, Kph, Vp, Wvp, bvp, ctxl, ctxcb);
  {
    dim3 g(32, 8);
    gemm_wo<<<g, 256, 0, stream>>>(ctxcb, Wobf, bo, hbf, outF);
  }
  ln_kernel<<<4096, 256, 0, stream>>>(outF, lng, lnb);
}